// Round 11
// baseline (971.202 us; speedup 1.0000x reference)
//
#include <hip/hip_runtime.h>

typedef _Float16 f16;
typedef _Float16 f16x2 __attribute__((ext_vector_type(2)));
typedef _Float16 f16x4 __attribute__((ext_vector_type(4)));
typedef _Float16 f16x8 __attribute__((ext_vector_type(8)));
typedef float    f32x4 __attribute__((ext_vector_type(4)));
typedef int      i32x4 __attribute__((ext_vector_type(4)));
typedef unsigned int u32;
typedef unsigned short u16;

#define DEVI static __device__ __forceinline__

static constexpr int LDT = 40;    // lds row stride (halves) for 64x32 tiles (+8 pad)
static constexpr int LDA = 264;   // lds row stride for 64x256 resident A tiles

DEVI float tanh_c(float x){
  x = fminf(fmaxf(x, -15.f), 15.f);
  float e = __expf(2.f*x);
  return (e - 1.f)/(e + 1.f);
}
DEVI float sig_f(float x){ return __builtin_amdgcn_rcpf(1.f + __expf(-x)); }
DEVI float tanh_f(float x){ return 1.f - 2.f*__builtin_amdgcn_rcpf(1.f + __expf(2.f*x)); }
DEVI float wmax16(float v){
  #pragma unroll
  for (int m=1;m<16;m<<=1) v = fmaxf(v, __shfl_xor(v, m, 64));
  return v;
}
DEVI float wsum16(float v){
  #pragma unroll
  for (int m=1;m<16;m<<=1) v += __shfl_xor(v, m, 64);
  return v;
}
DEVI f16x8 frag_ld(const f16* p){ return *(const f16x8*)p; }
DEVI void stage_tileh(int t256, const f16* src, int ld, f16* dst){
  int row = t256>>2, qq = t256&3;
  *(f16x8*)(dst + row*LDT + qq*8) = *(const f16x8*)(src + (size_t)row*ld + qq*8);
}
#define ZERO4(acc) { f32x4 _z = {0.f,0.f,0.f,0.f}; acc[0]=_z; acc[1]=_z; acc[2]=_z; acc[3]=_z; }

// 64x64 NT MFMA tile (t256 = thread id within the 256-thread tile team)
DEVI void gemm64h(int t256, const f16* A, int lda, const f16* Bm, int ldb, int K,
                  f16* lA, f16* lB, f32x4 acc[4]){
  const int lane = t256 & 63, wv = t256 >> 6;
  const int l15 = lane & 15, kq = lane >> 4;
  for (int k0=0; k0<K; k0+=32){
    __syncthreads();
    stage_tileh(t256, A + k0, lda, lA);
    stage_tileh(t256, Bm + k0, ldb, lB);
    __syncthreads();
    f16x8 af = frag_ld(lA + (16*wv + l15)*LDT + kq*8);
    #pragma unroll
    for (int nt=0; nt<4; nt++){
      f16x8 bf = frag_ld(lB + (16*nt + l15)*LDT + kq*8);
      acc[nt] = __builtin_amdgcn_mfma_f32_16x16x32_f16(af, bf, acc[nt], 0,0,0);
    }
  }
}

// ---------------- fused prep job bodies ----------------
DEVI void wmax_job(int bid, int tid, const float* Whh, u32* ws){
  int i = (bid*256 + tid)*4;
  float m = 0.f;
  #pragma unroll
  for (int j=0;j<4;j++) m = fmaxf(m, fabsf(Whh[i+j]));
  #pragma unroll
  for (int d=1; d<64; d<<=1) m = fmaxf(m, __shfl_xor(m, d, 64));
  if ((tid & 63) == 0) atomicMax(ws, __float_as_uint(m));
}
// quantize Whh into gate-packed i8 MFMA A-fragments (v8 map).
DEVI void wq8_job(int bid, int l, const float* Whh, const u32* ws, i32x4* Wq){
  const int kt = bid & 3, t8 = (bid >> 2) & 7, w = bid >> 5;
  const int r15 = l & 15;
  const int u4 = r15 >> 2, g = r15 & 3;
  const int unit = w*32 + t8*4 + u4;
  const int row = g*256 + unit;
  const int k0  = kt*64 + (l >> 4)*16;
  const float scale = 127.f / __uint_as_float(ws[0]);
  int dw[4];
  #pragma unroll
  for (int d=0; d<4; d++){
    u32 acc = 0;
    #pragma unroll
    for (int j=0; j<4; j++){
      float q = __builtin_rintf(Whh[(size_t)row*256 + k0 + d*4 + j] * scale);
      int qi = (int)fminf(fmaxf(q, -127.f), 127.f);
      acc |= ((u32)qi & 0xffu) << (8*j);
    }
    dw[d] = (int)acc;
  }
  i32x4 v = { dw[0], dw[1], dw[2], dw[3] };
  Wq[(size_t)bid*64 + l] = v;
}

// prep1: pure input transforms (epad moved to mega_enc workers):
//   [0,16384) embx | [16384,16896) cvt eWih | [16896,17408) cvt dWih | [17408,17920) cvt Tm
//   [17920,18176) wmax e | [18176,18432) wmax d | [18432,19712) gconvT | [19712,21760) gdecT
__global__ void k_prep1(const int* __restrict__ xs, const int* __restrict__ ys,
                        const float* __restrict__ eemb, const float* __restrict__ demb,
                        f16* __restrict__ xemb, f16* __restrict__ yemb,
                        const float* __restrict__ eWih, f16* __restrict__ Wihe,
                        const float* __restrict__ dWih, f16* __restrict__ Wihd,
                        const float* __restrict__ Tm, f16* __restrict__ Tf,
                        const float* __restrict__ eWhh, const float* __restrict__ dWhh,
                        u32* __restrict__ wsc,
                        const float* __restrict__ gconv, f16* __restrict__ gcT,
                        const float* __restrict__ gdec, f16* __restrict__ gdT)
{
  const int bid = blockIdx.x, tid = threadIdx.x;
  if (bid < 16384){
    int id = bid*2 + (tid>>7); int f = tid & 127;
    bool dec = id >= 32*512; int id2 = dec ? id - 32*512 : id;
    int idx = dec ? ys[id2] : xs[id2];
    if (idx < 4) idx = 0;
    const float* src = (dec ? demb : eemb) + (size_t)idx*128;
    (dec ? yemb : xemb)[(size_t)id2*128 + f] = (f16)src[f];
  } else if (bid < 16896){
    int i = (bid-16384)*256 + tid; Wihe[i] = (f16)eWih[i];
  } else if (bid < 17408){
    int i = (bid-16896)*256 + tid; Wihd[i] = (f16)dWih[i];
  } else if (bid < 17920){
    int i = (bid-17408)*256 + tid; Tf[i] = (f16)Tm[i];
  } else if (bid < 18176){
    wmax_job(bid-17920, tid, eWhh, wsc + 0);
  } else if (bid < 18432){
    wmax_job(bid-18176, tid, dWhh, wsc + 1);
  } else if (bid < 19712){
    int idr = bid - 18432;               // 0..1279
    int fo = tid;
    gcT[(size_t)fo*1280 + idr] = (f16)gconv[(size_t)idr*256 + fo];
  } else {
    int v = bid - 19712;                 // 0..2047
    int f = tid;
    f16 val = (f16)0.f;
    if (v < 2000) val = (f16)gdec[(size_t)f*2000 + v];
    gdT[(size_t)v*256 + f] = val;
  }
}

// U output permuted to unit-major: col' = unit*4 + gate
DEVI void ku_body(int t256, int m0, int n0, const f16* X, const f16* Wih,
                  const float* bias, f16* U, f16* lA, f16* lB){
  f32x4 acc[4]; ZERO4(acc);
  gemm64h(t256, X + (size_t)m0*128, 128, Wih + (size_t)n0*128, 128, 128, lA, lB, acc);
  const int lane=t256&63, wv=t256>>6, l15=lane&15, kq=lane>>4;
  #pragma unroll
  for (int nt=0;nt<4;nt++){
    int n = n0 + nt*16 + l15;
    float bv = bias[n];
    int cnew = (n & 255)*4 + (n >> 8);
    #pragma unroll
    for (int r=0;r<4;r++)
      U[(size_t)(m0 + 16*wv + 4*kq + r)*1024 + cnew] = (f16)(acc[nt][r] + bv);
  }
}

DEVI void conv_body(int t256, int m0, int n0, const f16* epad, const f16* gcT, f16* tf,
                    f16* lA, f16* lB){
  const int b = m0 >> 9, n = m0 & 511;
  f32x4 acc[4]; ZERO4(acc);
  gemm64h(t256, epad + ((size_t)b*516 + n)*256, 256, gcT + (size_t)n0*1280, 1280, 1280, lA, lB, acc);
  const int lane=t256&63, wv=t256>>6, l15=lane&15, kq=lane>>4;
  #pragma unroll
  for (int nt=0;nt<4;nt++)
    #pragma unroll
    for (int r=0;r<4;r++)
      tf[(size_t)(m0 + 16*wv + 4*kq + r)*256 + n0 + nt*16 + l15] = (f16)tanh_c(acc[nt][r]);
}

// prep2: [0,4096) k_u enc tiles | [4096,4352) wq8 e | [4352,4608) wq8 d
__global__ __launch_bounds__(256,4) void k_prep2(
    const f16* __restrict__ xemb, const f16* __restrict__ Wihe, const float* __restrict__ eb,
    f16* __restrict__ Uenc,
    const float* __restrict__ eWhh, const float* __restrict__ dWhh,
    const u32* __restrict__ wsc, i32x4* __restrict__ Wq8e, i32x4* __restrict__ Wq8d)
{
  __shared__ f16 lA[64*LDT], lB[64*LDT];
  const int bid = blockIdx.x;
  if (bid < 4096){
    ku_body(threadIdx.x, (bid>>4)*64, (bid&15)*64, xemb, Wihe, eb, Uenc, lA, lB);
  } else if (bid < 4352){
    if (threadIdx.x < 64) wq8_job(bid-4096, threadIdx.x, eWhh, wsc + 0, Wq8e);
  } else {
    if (threadIdx.x < 64) wq8_job(bid-4352, threadIdx.x, dWhh, wsc + 1, Wq8d);
  }
}

DEVI void th_body(int t256, int m0, int n0, const f16* henh, const f16* Tf, f16* Th,
                  f16* lA, f16* lB){
  f32x4 acc[4]; ZERO4(acc);
  gemm64h(t256, henh + (size_t)m0*512, 512, Tf + (size_t)n0*512, 512, 512, lA, lB, acc);
  const int lane=t256&63, wv=t256>>6, l15=lane&15, kq=lane>>4;
  #pragma unroll
  for (int nt=0;nt<4;nt++)
    #pragma unroll
    for (int r=0;r<4;r++)
      Th[(size_t)(m0 + 16*wv + 4*kq + r)*256 + n0 + nt*16 + l15] = (f16)acc[nt][r];
}

// pass1 (512-thr): halves split the 8 n-chunks; shared lA; per-half lB/mx/se; merged at end
DEVI void pass1_body(int tid, int mt, int ns, const f16* tf, const f16* gdT,
                     float* mxp, float* sep, f16* lA, f16* lB2, float* mxs2, float* ses2){
  const int half = tid >> 8, t256 = tid & 255;
  const int lane = tid & 63, wv = t256 >> 6, l15 = lane & 15, kq = lane >> 4;
  f16* lB = lB2 + half*(64*LDT);
  {
    const f16* A = tf + (size_t)mt*64*256;
    int row = tid >> 3, c8 = tid & 7;
    #pragma unroll
    for (int q=0;q<4;q++)
      *(f16x8*)(lA + row*LDA + c8*32 + q*8) = *(const f16x8*)(A + (size_t)row*256 + c8*32 + q*8);
  }
  if (t256 < 64){ mxs2[half*64 + t256] = -1e30f; ses2[half*64 + t256] = 0.f; }
  __syncthreads();
  for (int nci=0; nci<4; nci++){
    const int nc = half*4 + nci;
    const int nbase = ns*512 + nc*64;
    const f16* Bm = gdT + (size_t)nbase*256;
    f32x4 acc[4]; ZERO4(acc);
    for (int k0=0; k0<256; k0+=32){
      __syncthreads();
      stage_tileh(t256, Bm + k0, 256, lB);
      __syncthreads();
      f16x8 af = frag_ld(lA + (16*wv + l15)*LDA + k0 + kq*8);
      #pragma unroll
      for (int nt=0; nt<4; nt++){
        f16x8 bf = frag_ld(lB + (16*nt + l15)*LDT + kq*8);
        acc[nt] = __builtin_amdgcn_mfma_f32_16x16x32_f16(af, bf, acc[nt], 0,0,0);
      }
    }
    #pragma unroll
    for (int r=0;r<4;r++){
      float av[4]; float cm = -1e30f;
      #pragma unroll
      for (int nt=0;nt<4;nt++){
        int gcol = nbase + nt*16 + l15;
        float a = (gcol < 2000) ? acc[nt][r] : -1e30f;
        av[nt] = a; cm = fmaxf(cm, a);
      }
      cm = wmax16(cm);
      int rr = half*64 + 16*wv + 4*kq + r;
      float old = mxs2[rr];
      float nm = fmaxf(old, cm);
      float ss = 0.f;
      #pragma unroll
      for (int nt=0;nt<4;nt++) ss += __expf(av[nt] - nm);
      ss = wsum16(ss);
      if (l15 == 0){
        ses2[rr] = ses2[rr]*__expf(old - nm) + ss;
        mxs2[rr] = nm;
      }
    }
  }
  __syncthreads();
  if (tid < 64){
    float m0 = mxs2[tid], m1 = mxs2[64+tid];
    float nm = fmaxf(m0, m1);
    float se = ses2[tid]*__expf(m0-nm) + ses2[64+tid]*__expf(m1-nm);
    mxp[(size_t)ns*16384 + mt*64 + tid] = nm;
    sep[(size_t)ns*16384 + mt*64 + tid] = se;
  }
}

// pass2 with comb1 folded in: per-row running (mx, 1/se) computed from mxp/sep partials.
DEVI void pass2_body(int t256, int it, int jt, int b, const f16* tf, const f16* gdT,
                     const int* ys, const float* mxp, const float* sep, f16* scT,
                     f16* lA, f16* lB, int* jv, float* mxL, float* rseL){
  const int lane=t256&63, wv=t256>>6, l15=lane&15, kq=lane>>4;
  if (t256<64){
    jv[t256] = ys[b*512 + jt*64 + t256];
    int m = b*512 + it*64 + t256;
    float a0 = mxp[m], a1 = mxp[16384+m], a2 = mxp[2*16384+m], a3 = mxp[3*16384+m];
    float best = fmaxf(fmaxf(a0,a1), fmaxf(a2,a3));
    float sv = sep[m]*__expf(a0-best) + sep[16384+m]*__expf(a1-best)
             + sep[2*16384+m]*__expf(a2-best) + sep[3*16384+m]*__expf(a3-best);
    mxL[t256] = best; rseL[t256] = 1.f/sv;
  }
  const f16* A = tf + ((size_t)b*512 + it*64)*256;
  f32x4 acc[4]; ZERO4(acc);
  for (int k0=0;k0<256;k0+=32){
    __syncthreads();
    stage_tileh(t256, A + k0, 256, lA);
    { int row=t256>>2, qq=t256&3;
      *(f16x8*)(lB + row*LDT + qq*8) = *(const f16x8*)(gdT + (size_t)jv[row]*256 + k0 + qq*8); }
    __syncthreads();
    f16x8 af = frag_ld(lA + (16*wv+l15)*LDT + kq*8);
    #pragma unroll
    for (int nt=0;nt<4;nt++){
      f16x8 bf = frag_ld(lB + (16*nt+l15)*LDT + kq*8);
      acc[nt] = __builtin_amdgcn_mfma_f32_16x16x32_f16(af, bf, acc[nt], 0,0,0);
    }
  }
  float mxv[4], rsev[4];
  #pragma unroll
  for (int r=0;r<4;r++){
    int il = 16*wv + 4*kq + r;
    mxv[r] = mxL[il];
    rsev[r] = rseL[il];
  }
  #pragma unroll
  for (int nt=0;nt<4;nt++){
    int j_ = jt*64 + nt*16 + l15;
    #pragma unroll
    for (int r=0;r<4;r++){
      int i_ = it*64 + 16*wv + 4*kq + r;
      scT[((size_t)b*512 + j_)*512 + i_] = (f16)(__expf(acc[nt][r] - mxv[r]) * rsev[r]);
    }
  }
}

__global__ __launch_bounds__(256,2) void k_final(const f16* __restrict__ hdec, const f16* __restrict__ Th,
                                                 const f16* __restrict__ scT,
                                                 float* __restrict__ pmx, float* __restrict__ pden, float* __restrict__ pnum){
  __shared__ f16 lA[64*LDA];
  __shared__ f16 lB[64*LDT];
  __shared__ float mx_s[64], den_s[64], num_s[64];
  const int is = blockIdx.x, jt = blockIdx.y, b = blockIdx.z;
  const int tid = threadIdx.x, lane=tid&63, wv=tid>>6, l15=lane&15, kq=lane>>4;
  {
    const f16* A = hdec + ((size_t)b*512 + jt*64)*256;
    int row = tid>>2, qq = tid&3;
    #pragma unroll
    for (int c=0;c<8;c++)
      *(f16x8*)(lA + row*LDA + c*32 + qq*8) = *(const f16x8*)(A + (size_t)row*256 + c*32 + qq*8);
  }
  if (tid<64){ mx_s[tid]=-1e30f; den_s[tid]=0.f; num_s[tid]=0.f; }
  __syncthreads();
  for (int ic=0; ic<4; ic++){
    const int i0 = is*256 + ic*64;
    const f16* Bm = Th + ((size_t)b*512 + i0)*256;
    f32x4 acc[4]; ZERO4(acc);
    for (int k0=0;k0<256;k0+=32){
      __syncthreads();
      stage_tileh(tid, Bm + k0, 256, lB);
      __syncthreads();
      f16x8 af = frag_ld(lA + (16*wv+l15)*LDA + k0 + kq*8);
      #pragma unroll
      for (int nt=0;nt<4;nt++){
        f16x8 bf = frag_ld(lB + (16*nt+l15)*LDT + kq*8);
        acc[nt] = __builtin_amdgcn_mfma_f32_16x16x32_f16(af, bf, acc[nt], 0,0,0);
      }
    }
    #pragma unroll
    for (int r=0;r<4;r++){
      int jl = 16*wv + 4*kq + r;
      float av[4]; float cm=-1e30f;
      #pragma unroll
      for (int nt=0;nt<4;nt++){ av[nt]=acc[nt][r]; cm=fmaxf(cm,av[nt]); }
      cm = wmax16(cm);
      float old = mx_s[jl], nm = fmaxf(old, cm);
      float ds=0.f, nsum=0.f;
      const size_t srow = ((size_t)b*512 + jt*64 + jl)*512;
      #pragma unroll
      for (int nt=0;nt<4;nt++){
        float e = __expf(av[nt]-nm);
        float sc = (float)scT[srow + i0 + nt*16 + l15];
        ds += e; nsum += sc*e;
      }
      ds = wsum16(ds); nsum = wsum16(nsum);
      if (l15==0){
        float fac = __expf(old-nm);
        den_s[jl] = den_s[jl]*fac + ds;
        num_s[jl] = num_s[jl]*fac + nsum;
        mx_s[jl] = nm;
      }
    }
  }
  __syncthreads();
  if (tid<64){
    size_t idx = (((size_t)b*512) + jt*64 + tid)*2 + is;
    pmx[idx]=mx_s[tid]; pden[idx]=den_s[tid]; pnum[idx]=num_s[tid];
  }
}

__global__ void k_comb2(const float* __restrict__ pmx, const float* __restrict__ pden,
                        const float* __restrict__ pnum, float* __restrict__ out){
  const int b = blockIdx.x, j = threadIdx.x;    // 32 x 512
  size_t base = ((size_t)b*512 + j)*2;
  float m0=pmx[base], m1=pmx[base+1];
  float m = fmaxf(m0,m1);
  float e0=__expf(m0-m), e1=__expf(m1-m);
  float den = pden[base]*e0 + pden[base+1]*e1;
  float num = pnum[base]*e0 + pnum[base+1]*e1;
  float lp = __logf(num) - __logf(den);
  __shared__ float red[512];
  red[j] = lp;
  __syncthreads();
  for (int st=256; st>0; st>>=1){ if (j<st) red[j]+=red[j+st]; __syncthreads(); }
  if (j==0) atomicAdd(out, -red[0]);
}

// ---------------- LSTM v13: 2 seqs/block, 1 cell/thread (halved VALU phase) ----------------
// (verified R8: enc 389us, per-step ~1822cy = MFMA 1306 + VALU ~350 + exchange ~170)
DEVI void lstm_core(char* smem, const f16* U, const i32x4* Wq, const u32* ws,
                    u16* hout, float* hTcT, u16* hdec0, int nsteps, int mode, int bid)
{
  char* h8b = smem;                  // 2 buffers x 512 B
  const int tid = threadIdx.x;
  const int lane = tid & 63, w = tid >> 6;
  const int l15 = lane & 15, kq = lane >> 4;
  const int s = l15 & 1;             // sequence (2 per block)
  const int r = l15 >> 1;            // replica index -> owned tile 0..7
  const int u = w*32 + r*4 + kq;     // this thread's unit

  int dir = 0, b0;
  if (mode == 0){ dir = bid >> 4; b0 = (bid & 15)*2; }
  else b0 = bid*2;

  const float zscale = __uint_as_float(ws[0]) * (1.f/(127.f*127.f));

  i32x4 aw[32];
  #pragma unroll
  for (int f=0; f<32; f++) aw[f] = Wq[(size_t)(w*32 + f)*64 + lane];

  float c = 0.f;
  if (mode == 0){
    if (tid < 256) ((u32*)h8b)[tid] = 0u;   // 256 words = both 512B buffers
  } else {
    const float* hp = hTcT + (size_t)(b0+s)*512;
    float h0 = hp[u];
    c = hp[256 + u];
    h8b[((u>>4)*2 + s)*16 + (u&15)] = (char)(int)__builtin_rintf(h0*127.f);
  }

  // this thread's private U row base (unit-major cols: unit*4+gate)
  const f16* Urow = U + (size_t)(b0+s)*512*1024;
  f16x4 uv;
  {
    int tp0 = dir ? (nsteps-1) : 0;
    uv = *(const f16x4*)(Urow + (size_t)tp0*1024 + u*4);
  }
  __syncthreads();

  int cur = 0;
  #pragma unroll 1
  for (int t=0; t<nsteps; ++t){
    const int tpos = dir ? (nsteps-1-t) : t;
    int tn = dir ? (nsteps-2-t >= 0 ? nsteps-2-t : 0) : (t+1 < nsteps ? t+1 : nsteps-1);
    f16x4 pu = *(const f16x4*)(Urow + (size_t)tn*1024 + u*4);

    const char* hc = h8b + cur*512;
    i32x4 bf[4];
    #pragma unroll
    for (int kt=0; kt<4; kt++)
      bf[kt] = *(const i32x4*)(hc + ((kt*4 + kq)*2 + s)*16);

    i32x4 acc[8];
    #pragma unroll
    for (int t8=0; t8<8; t8++){
      i32x4 d = {0,0,0,0};
      #pragma unroll
      for (int kt=0; kt<4; kt++)
        d = __builtin_amdgcn_mfma_i32_16x16x64_i8(aw[t8*4+kt], bf[kt], d, 0,0,0);
      acc[t8] = d;
    }

    // pick tile r (7-select tree per element)
    i32x4 v;
    #pragma unroll
    for (int e=0; e<4; e++){
      int x01 = (r&1) ? acc[1][e] : acc[0][e];
      int x23 = (r&1) ? acc[3][e] : acc[2][e];
      int x45 = (r&1) ? acc[5][e] : acc[4][e];
      int x67 = (r&1) ? acc[7][e] : acc[6][e];
      int y0  = (r&2) ? x23 : x01;
      int y1  = (r&2) ? x67 : x45;
      v[e] = (r&4) ? y1 : y0;
    }

    float h_;
    {
      float z0 = fmaf((float)v[0], zscale, (float)uv[0]);
      float z1 = fmaf((float)v[1], zscale, (float)uv[1]);
      float z2 = fmaf((float)v[2], zscale, (float)uv[2]);
      float z3 = fmaf((float)v[3], zscale, (float)uv[3]);
      c  = sig_f(z1)*c + sig_f(z0)*tanh_f(z2);
      h_ = sig_f(z3)*tanh_f(c);
    }

    const int nxt = cur ^ 1;
    char* hn = h8b + nxt*512;
    hn[((u>>4)*2 + s)*16 + (u&15)] = (char)(int)__builtin_rintf(h_*127.f);

    f16 fh = (f16)h_;
    if (mode == 0){
      hout[(((size_t)(b0+s)*512 + tpos)*512) + dir*256 + u] = __builtin_bit_cast(u16, fh);
      if (!dir && t == nsteps-1){
        hdec0[(size_t)(b0+s)*512*256 + u] = __builtin_bit_cast(u16, fh);
        float* hp = hTcT + (size_t)(b0+s)*512;
        hp[u] = h_; hp[256+u] = c;
      }
    } else {
      hout[((size_t)(b0+s)*512 + (t+1))*256 + u] = __builtin_bit_cast(u16, fh);
    }

    // lgkm-only barrier: LDS h-exchange must be visible; global stores stay in flight.
    asm volatile("s_waitcnt lgkmcnt(0)" ::: "memory");
    __builtin_amdgcn_s_barrier();
    asm volatile("" ::: "memory");
    __builtin_amdgcn_sched_barrier(0);

    cur = nxt;
    uv = pu;
  }
}

// ---------------- mega dispatches: persistent-worker grids ----------------
// mega_enc absorbs epad+conv via OWNERSHIP-ALIGNED ordering (no cross-block gates —
// R9 lesson): worker wk<256 owns tf row-block mt=wk; it computes epad rows for mt,
// __threadfence (L1 inv) + sync, conv 4 tiles for mt, fence+sync, then pass1(mt,*)
// which reads ONLY tf rows of mt. Overlapping epad rows across workers write identical
// values (benign). Deadlock-impossible; occupancy loss would be perf-only.
__global__ __launch_bounds__(512,2) void k_mega_enc(
    const f16* __restrict__ Uenc, const i32x4* __restrict__ Wqe, const u32* __restrict__ wse,
    u16* __restrict__ henh, float* __restrict__ hTcT, u16* __restrict__ hdec0,
    f16* __restrict__ tf, const f16* __restrict__ gdT,
    float* __restrict__ mxp, float* __restrict__ sep,
    const f16* __restrict__ yemb, const f16* __restrict__ Wihd,
    const float* __restrict__ db, f16* __restrict__ Udec,
    const int* __restrict__ xs, const float* __restrict__ gemb, f16* __restrict__ epad,
    const f16* __restrict__ gcT)
{
  __shared__ __align__(16) char smem[45056];
  const int bid = blockIdx.x;
  const int tid = threadIdx.x;
  if (bid < 32){
    lstm_core(smem, Uenc, Wqe, wse, henh, hTcT, hdec0, 512, 0, bid);
    return;
  }
  const int wk = bid - 32;               // 0..479
  if (wk < 256){
    const int mt = wk;                   // owned tf row-block
    const int b = mt >> 3, n = (mt & 7)*64;
    // epad rows p = n .. n+67 (68 rows; conv window needs +4)
    #pragma unroll 1
    for (int rr = 0; rr < 34; rr++){
      int p = n + rr*2 + (tid>>8);
      int f = tid & 255;
      float val = 0.f;
      if (p >= 2 && p < 514){ int idx = xs[b*512 + p - 2]; val = tanh_c(gemb[(size_t)idx*256 + f]); }
      epad[((size_t)b*516 + p)*256 + f] = (f16)val;
    }
    __threadfence();
    __syncthreads();
    // conv 4 tiles for mt (dual-team)
    {
      const int half = tid >> 8, t256 = tid & 255;
      char* base = smem + half*10240;
      #pragma unroll 1
      for (int it2 = 0; it2 < 2; it2++){
        __syncthreads();
        int n0 = it2*2 + half;           // 0..3
        conv_body(t256, mt*64, n0*64, epad, gcT, tf, (f16*)base, (f16*)(base + 5120));
      }
    }
    __threadfence();
    __syncthreads();
    // pass1 4 jobs for mt
    #pragma unroll 1
    for (int ns = 0; ns < 4; ns++){
      __syncthreads();
      pass1_body(tid, mt, ns, tf, gdT, mxp, sep,
                 (f16*)smem, (f16*)(smem + 33792), (float*)(smem + 44032), (float*)(smem + 44544));
    }
  }
  // ku-dec (2048 dual-team jobs), all 480 workers stride
  {
    const int half = tid >> 8, t256 = tid & 255;
    char* base = smem + half*10240;
    #pragma unroll 1
    for (int v = wk; v < 2048; v += 480){
      __syncthreads();
      int vbm = v >> 4, ny = v & 15;
      int m0 = (vbm*2 + half)*64;
      int n0 = ny*64;
      ku_body(t256, m0, n0, yemb, Wihd, db, Udec, (f16*)base, (f16*)(base + 5120));
    }
  }
}

__global__ __launch_bounds__(512,2) void k_mega_dec(
    const f16* __restrict__ Udec, const i32x4* __restrict__ Wqd, const u32* __restrict__ wsd,
    u16* __restrict__ hdec, float* __restrict__ hTcT,
    const f16* __restrict__ tf, const f16* __restrict__ gdT, const int* __restrict__ ys,
    const float* __restrict__ mxp, const float* __restrict__ sep, f16* __restrict__ scT,
    const f16* __restrict__ henh, const f16* __restrict__ Tf, f16* __restrict__ Th)
{
  __shared__ __align__(16) char smem[24576];
  const int bid = blockIdx.x;
  const int tid = threadIdx.x;
  if (bid < 16){
    lstm_core(smem, Udec, Wqd, wsd, hdec, hTcT, hdec, 511, 1, bid);
    return;
  }
  const int w = bid - 16;                // 0..495
  #pragma unroll 1
  for (int v = w; v < 1536; v += 496){
    __syncthreads();                      // smem reuse fence between jobs
    if (v < 1024){
      int half = tid >> 8, t256 = tid & 255;
      int b = v >> 5, rem = v & 31;
      int jt = rem >> 2, it = (rem & 3)*2 + half;
      char* base = smem + half*11008;
      pass2_body(t256, it, jt, b, tf, gdT, ys, mxp, sep, scT,
                 (f16*)base, (f16*)(base + 5120), (int*)(base + 10240),
                 (float*)(base + 10496), (float*)(base + 10752));
    } else {
      int vb = v - 1024;                  // 0..511
      int half = tid >> 8, t256 = tid & 255;
      int m0 = ((vb >> 2)*2 + half)*64;
      int n0 = (vb & 3)*64;
      char* base = smem + half*10240;
      th_body(t256, m0, n0, henh, Tf, Th, (f16*)base, (f16*)(base + 5120));
    }
  }
}

// ---------------- host ----------------
extern "C" void kernel_launch(void* const* d_in, const int* in_sizes, int n_in,
                              void* d_out, int out_size, void* d_ws, size_t ws_size,
                              hipStream_t stream)
{
  (void)in_sizes; (void)n_in; (void)out_size;
  const int*   xs    = (const int*)d_in[0];
  const int*   ys    = (const int*)d_in[1];
  const float* gemb  = (const float*)d_in[2];
  const float* gconv = (const float*)d_in[3];
  const float* gdec  = (const float*)d_in[4];
  const float* eemb  = (const float*)d_in[5];
  const float* demb  = (const float*)d_in[6];
  const float* eWih  = (const float*)d_in[7];
  const float* eWhh  = (const float*)d_in[8];
  const float* eb    = (const float*)d_in[9];
  const float* dWih  = (const float*)d_in[10];
  const float* dWhh  = (const float*)d_in[11];
  const float* db    = (const float*)d_in[12];
  const float* Tm    = (const float*)d_in[13];

  char* wsb = (char*)d_ws;
  size_t off = 0;
  auto take = [&](size_t bytes)->char*{ char* p = wsb + off; off += (bytes + 255) & ~(size_t)255; return p; };
  f16* epad  = (f16*)take((size_t)32*516*256*2);
  f16* tf    = (f16*)take((size_t)32*512*256*2);
  f16* xemb  = (f16*)take((size_t)32*512*128*2);
  f16* yemb  = (f16*)take((size_t)32*512*128*2);
  f16* Uenc  = (f16*)take((size_t)32*512*1024*2);
  f16* Udec  = (f16*)take((size_t)32*512*1024*2);
  f16* henh  = (f16*)take((size_t)32*512*512*2);
  f16* hdec  = (f16*)take((size_t)32*512*256*2);
  f16* Th    = (f16*)take((size_t)32*512*256*2);
  f16* scT   = (f16*)take((size_t)32*512*512*2);
  float* mxp = (float*)take((size_t)4*16384*4);
  float* sep = (float*)take((size_t)4*16384*4);
  float* pmx = (float*)take((size_t)32*512*2*4);
  float* pden= (float*)take((size_t)32*512*2*4);
  float* pnum= (float*)take((size_t)32*512*2*4);
  float* hTcT= (float*)take((size_t)32*512*4);
  f16* Wihe  = (f16*)take((size_t)1024*128*2);
  f16* Wihd  = (f16*)take((size_t)1024*128*2);
  f16* Tf    = (f16*)take((size_t)256*512*2);
  f16* gcT   = (f16*)take((size_t)256*1280*2);
  f16* gdT   = (f16*)take((size_t)2048*256*2);
  i32x4* Wq8e = (i32x4*)take((size_t)256*64*16);
  i32x4* Wq8d = (i32x4*)take((size_t)256*64*16);
  u32* wsc   = (u32*)take(16);
  if (off > ws_size) return;

  hipMemsetAsync(d_out, 0, sizeof(float), stream);
  hipMemsetAsync(wsc, 0, 16, stream);

  // fused prep 1: embx | cvt x3 | wmax x2 | gconvT | gdecT
  k_prep1<<<dim3(21760), 256, 0, stream>>>(xs, ys, eemb, demb, xemb, yemb,
                                           eWih, Wihe, dWih, Wihd, Tm, Tf,
                                           eWhh, dWhh, wsc,
                                           gconv, gcT, gdec, gdT);
  // fused prep 2: k_u enc | wq8 x2
  k_prep2<<<dim3(4608), 256, 0, stream>>>(xemb, Wihe, eb, Uenc, eWhh, dWhh, wsc,
                                          Wq8e, Wq8d);

  // mega-enc (persistent, 512 blocks): [0,32) lstm_enc | workers: epad->conv->pass1 (owned) + ku-dec
  k_mega_enc<<<dim3(512), 512, 0, stream>>>(Uenc, Wq8e, wsc + 0, (u16*)henh, hTcT, (u16*)hdec,
                                            tf, gdT, mxp, sep, yemb, Wihd, db, Udec,
                                            xs, gemb, epad, gcT);

  // mega-dec (persistent, 512 blocks): [0,16) lstm_dec | workers: 1024 pass2 (comb1 folded) + 512 th
  k_mega_dec<<<dim3(512), 512, 0, stream>>>(Udec, Wq8d, wsc + 1, (u16*)hdec, hTcT,
                                            tf, gdT, ys, mxp, sep, scT, henh, Tf, Th);

  k_final<<<dim3(2,8,32), 256, 0, stream>>>(hdec, Th, scT, pmx, pden, pnum);
  k_comb2<<<dim3(32), 512, 0, stream>>>(pmx, pden, pnum, (float*)d_out);
}

// Round 13
// 950.947 us; speedup vs baseline: 1.0213x; 1.0213x over previous
//
#include <hip/hip_runtime.h>

typedef _Float16 f16;
typedef _Float16 f16x2 __attribute__((ext_vector_type(2)));
typedef _Float16 f16x4 __attribute__((ext_vector_type(4)));
typedef _Float16 f16x8 __attribute__((ext_vector_type(8)));
typedef float    f32x4 __attribute__((ext_vector_type(4)));
typedef int      i32x4 __attribute__((ext_vector_type(4)));
typedef unsigned int u32;
typedef unsigned short u16;

#define DEVI static __device__ __forceinline__

static constexpr int LDT = 40;    // lds row stride (halves) for 64x32 tiles (+8 pad)
static constexpr int LDA = 264;   // lds row stride for 64x256 resident A tiles

DEVI float tanh_c(float x){
  x = fminf(fmaxf(x, -15.f), 15.f);
  float e = __expf(2.f*x);
  return (e - 1.f)/(e + 1.f);
}
DEVI float sig_f(float x){ return __builtin_amdgcn_rcpf(1.f + __expf(-x)); }
DEVI float tanh_f(float x){ return 1.f - 2.f*__builtin_amdgcn_rcpf(1.f + __expf(2.f*x)); }
DEVI float wmax16(float v){
  #pragma unroll
  for (int m=1;m<16;m<<=1) v = fmaxf(v, __shfl_xor(v, m, 64));
  return v;
}
DEVI float wsum16(float v){
  #pragma unroll
  for (int m=1;m<16;m<<=1) v += __shfl_xor(v, m, 64);
  return v;
}
DEVI f16x8 frag_ld(const f16* p){ return *(const f16x8*)p; }
DEVI void stage_tileh(int t256, const f16* src, int ld, f16* dst){
  int row = t256>>2, qq = t256&3;
  *(f16x8*)(dst + row*LDT + qq*8) = *(const f16x8*)(src + (size_t)row*ld + qq*8);
}
#define ZERO4(acc) { f32x4 _z = {0.f,0.f,0.f,0.f}; acc[0]=_z; acc[1]=_z; acc[2]=_z; acc[3]=_z; }

// 64x64 NT MFMA tile (t256 = thread id within the 256-thread tile team)
DEVI void gemm64h(int t256, const f16* A, int lda, const f16* Bm, int ldb, int K,
                  f16* lA, f16* lB, f32x4 acc[4]){
  const int lane = t256 & 63, wv = t256 >> 6;
  const int l15 = lane & 15, kq = lane >> 4;
  for (int k0=0; k0<K; k0+=32){
    __syncthreads();
    stage_tileh(t256, A + k0, lda, lA);
    stage_tileh(t256, Bm + k0, ldb, lB);
    __syncthreads();
    f16x8 af = frag_ld(lA + (16*wv + l15)*LDT + kq*8);
    #pragma unroll
    for (int nt=0; nt<4; nt++){
      f16x8 bf = frag_ld(lB + (16*nt + l15)*LDT + kq*8);
      acc[nt] = __builtin_amdgcn_mfma_f32_16x16x32_f16(af, bf, acc[nt], 0,0,0);
    }
  }
}

// ---------------- fused prep job bodies ----------------
DEVI void wmax_job(int bid, int tid, const float* Whh, u32* ws){
  int i = (bid*256 + tid)*4;
  float m = 0.f;
  #pragma unroll
  for (int j=0;j<4;j++) m = fmaxf(m, fabsf(Whh[i+j]));
  #pragma unroll
  for (int d=1; d<64; d<<=1) m = fmaxf(m, __shfl_xor(m, d, 64));
  if ((tid & 63) == 0) atomicMax(ws, __float_as_uint(m));
}
// quantize Whh into gate-packed i8 MFMA A-fragments (v8 map).
DEVI void wq8_job(int bid, int l, const float* Whh, const u32* ws, i32x4* Wq){
  const int kt = bid & 3, t8 = (bid >> 2) & 7, w = bid >> 5;
  const int r15 = l & 15;
  const int u4 = r15 >> 2, g = r15 & 3;
  const int unit = w*32 + t8*4 + u4;
  const int row = g*256 + unit;
  const int k0  = kt*64 + (l >> 4)*16;
  const float scale = 127.f / __uint_as_float(ws[0]);
  int dw[4];
  #pragma unroll
  for (int d=0; d<4; d++){
    u32 acc = 0;
    #pragma unroll
    for (int j=0; j<4; j++){
      float q = __builtin_rintf(Whh[(size_t)row*256 + k0 + d*4 + j] * scale);
      int qi = (int)fminf(fmaxf(q, -127.f), 127.f);
      acc |= ((u32)qi & 0xffu) << (8*j);
    }
    dw[d] = (int)acc;
  }
  i32x4 v = { dw[0], dw[1], dw[2], dw[3] };
  Wq[(size_t)bid*64 + l] = v;
}

// prep1: ALL pure input transforms fused (R10 placement):
//   [0,16384) embx | [16384,16896) cvt eWih | [16896,17408) cvt dWih | [17408,17920) cvt Tm
//   [17920,18176) wmax e | [18176,18432) wmax d | [18432,34944) epad | [34944,36224) gconvT
//   [36224,38272) gdecT
__global__ void k_prep1(const int* __restrict__ xs, const int* __restrict__ ys,
                        const float* __restrict__ eemb, const float* __restrict__ demb,
                        f16* __restrict__ xemb, f16* __restrict__ yemb,
                        const float* __restrict__ eWih, f16* __restrict__ Wihe,
                        const float* __restrict__ dWih, f16* __restrict__ Wihd,
                        const float* __restrict__ Tm, f16* __restrict__ Tf,
                        const float* __restrict__ eWhh, const float* __restrict__ dWhh,
                        u32* __restrict__ wsc,
                        const float* __restrict__ gemb, f16* __restrict__ epad,
                        const float* __restrict__ gconv, f16* __restrict__ gcT,
                        const float* __restrict__ gdec, f16* __restrict__ gdT)
{
  const int bid = blockIdx.x, tid = threadIdx.x;
  if (bid < 16384){
    int id = bid*2 + (tid>>7); int f = tid & 127;
    bool dec = id >= 32*512; int id2 = dec ? id - 32*512 : id;
    int idx = dec ? ys[id2] : xs[id2];
    if (idx < 4) idx = 0;
    const float* src = (dec ? demb : eemb) + (size_t)idx*128;
    (dec ? yemb : xemb)[(size_t)id2*128 + f] = (f16)src[f];
  } else if (bid < 16896){
    int i = (bid-16384)*256 + tid; Wihe[i] = (f16)eWih[i];
  } else if (bid < 17408){
    int i = (bid-16896)*256 + tid; Wihd[i] = (f16)dWih[i];
  } else if (bid < 17920){
    int i = (bid-17408)*256 + tid; Tf[i] = (f16)Tm[i];
  } else if (bid < 18176){
    wmax_job(bid-17920, tid, eWhh, wsc + 0);
  } else if (bid < 18432){
    wmax_job(bid-18176, tid, dWhh, wsc + 1);
  } else if (bid < 34944){
    int row = bid - 18432;               // 0..16511
    int f = tid;
    int b = row / 516, p = row - b*516;
    float v = 0.f;
    if (p >= 2 && p < 514){ int idx = xs[b*512 + p - 2]; v = tanh_c(gemb[(size_t)idx*256 + f]); }
    epad[(size_t)row*256 + f] = (f16)v;
  } else if (bid < 36224){
    int idr = bid - 34944;               // 0..1279
    int fo = tid;
    gcT[(size_t)fo*1280 + idr] = (f16)gconv[(size_t)idr*256 + fo];
  } else {
    int v = bid - 36224;                 // 0..2047
    int f = tid;
    f16 val = (f16)0.f;
    if (v < 2000) val = (f16)gdec[(size_t)f*2000 + v];
    gdT[(size_t)v*256 + f] = val;
  }
}

// U output permuted to unit-major: col' = unit*4 + gate
DEVI void ku_body(int t256, int m0, int n0, const f16* X, const f16* Wih,
                  const float* bias, f16* U, f16* lA, f16* lB){
  f32x4 acc[4]; ZERO4(acc);
  gemm64h(t256, X + (size_t)m0*128, 128, Wih + (size_t)n0*128, 128, 128, lA, lB, acc);
  const int lane=t256&63, wv=t256>>6, l15=lane&15, kq=lane>>4;
  #pragma unroll
  for (int nt=0;nt<4;nt++){
    int n = n0 + nt*16 + l15;
    float bv = bias[n];
    int cnew = (n & 255)*4 + (n >> 8);
    #pragma unroll
    for (int r=0;r<4;r++)
      U[(size_t)(m0 + 16*wv + 4*kq + r)*1024 + cnew] = (f16)(acc[nt][r] + bv);
  }
}

DEVI void conv_body(int t256, int m0, int n0, const f16* epad, const f16* gcT, f16* tf,
                    f16* lA, f16* lB){
  const int b = m0 >> 9, n = m0 & 511;
  f32x4 acc[4]; ZERO4(acc);
  gemm64h(t256, epad + ((size_t)b*516 + n)*256, 256, gcT + (size_t)n0*1280, 1280, 1280, lA, lB, acc);
  const int lane=t256&63, wv=t256>>6, l15=lane&15, kq=lane>>4;
  #pragma unroll
  for (int nt=0;nt<4;nt++)
    #pragma unroll
    for (int r=0;r<4;r++)
      tf[(size_t)(m0 + 16*wv + 4*kq + r)*256 + n0 + nt*16 + l15] = (f16)tanh_c(acc[nt][r]);
}

// prep2 (R10 placement): [0,4096) k_u enc | [4096,4352) wq8 e | [4352,4608) wq8 d | [4608,5632) conv
__global__ __launch_bounds__(256,4) void k_prep2(
    const f16* __restrict__ xemb, const f16* __restrict__ Wihe, const float* __restrict__ eb,
    f16* __restrict__ Uenc,
    const float* __restrict__ eWhh, const float* __restrict__ dWhh,
    const u32* __restrict__ wsc, i32x4* __restrict__ Wq8e, i32x4* __restrict__ Wq8d,
    const f16* __restrict__ epad, const f16* __restrict__ gcT, f16* __restrict__ tf)
{
  __shared__ f16 lA[64*LDT], lB[64*LDT];
  const int bid = blockIdx.x;
  if (bid < 4096){
    ku_body(threadIdx.x, (bid>>4)*64, (bid&15)*64, xemb, Wihe, eb, Uenc, lA, lB);
  } else if (bid < 4352){
    if (threadIdx.x < 64) wq8_job(bid-4096, threadIdx.x, eWhh, wsc + 0, Wq8e);
  } else if (bid < 4608){
    if (threadIdx.x < 64) wq8_job(bid-4352, threadIdx.x, dWhh, wsc + 1, Wq8d);
  } else {
    int vb = bid - 4608;                 // 0..1023
    conv_body(threadIdx.x, (vb>>2)*64, (vb&3)*64, epad, gcT, tf, lA, lB);
  }
}

DEVI void th_body(int t256, int m0, int n0, const f16* henh, const f16* Tf, f16* Th,
                  f16* lA, f16* lB){
  f32x4 acc[4]; ZERO4(acc);
  gemm64h(t256, henh + (size_t)m0*512, 512, Tf + (size_t)n0*512, 512, 512, lA, lB, acc);
  const int lane=t256&63, wv=t256>>6, l15=lane&15, kq=lane>>4;
  #pragma unroll
  for (int nt=0;nt<4;nt++)
    #pragma unroll
    for (int r=0;r<4;r++)
      Th[(size_t)(m0 + 16*wv + 4*kq + r)*256 + n0 + nt*16 + l15] = (f16)acc[nt][r];
}

// pass1 (512-thr): halves split the 8 n-chunks; shared lA; per-half lB/mx/se; merged at end
DEVI void pass1_body(int tid, int mt, int ns, const f16* tf, const f16* gdT,
                     float* mxp, float* sep, f16* lA, f16* lB2, float* mxs2, float* ses2){
  const int half = tid >> 8, t256 = tid & 255;
  const int lane = tid & 63, wv = t256 >> 6, l15 = lane & 15, kq = lane >> 4;
  f16* lB = lB2 + half*(64*LDT);
  {
    const f16* A = tf + (size_t)mt*64*256;
    int row = tid >> 3, c8 = tid & 7;
    #pragma unroll
    for (int q=0;q<4;q++)
      *(f16x8*)(lA + row*LDA + c8*32 + q*8) = *(const f16x8*)(A + (size_t)row*256 + c8*32 + q*8);
  }
  if (t256 < 64){ mxs2[half*64 + t256] = -1e30f; ses2[half*64 + t256] = 0.f; }
  __syncthreads();
  for (int nci=0; nci<4; nci++){
    const int nc = half*4 + nci;
    const int nbase = ns*512 + nc*64;
    const f16* Bm = gdT + (size_t)nbase*256;
    f32x4 acc[4]; ZERO4(acc);
    for (int k0=0; k0<256; k0+=32){
      __syncthreads();
      stage_tileh(t256, Bm + k0, 256, lB);
      __syncthreads();
      f16x8 af = frag_ld(lA + (16*wv + l15)*LDA + k0 + kq*8);
      #pragma unroll
      for (int nt=0; nt<4; nt++){
        f16x8 bf = frag_ld(lB + (16*nt + l15)*LDT + kq*8);
        acc[nt] = __builtin_amdgcn_mfma_f32_16x16x32_f16(af, bf, acc[nt], 0,0,0);
      }
    }
    #pragma unroll
    for (int r=0;r<4;r++){
      float av[4]; float cm = -1e30f;
      #pragma unroll
      for (int nt=0;nt<4;nt++){
        int gcol = nbase + nt*16 + l15;
        float a = (gcol < 2000) ? acc[nt][r] : -1e30f;
        av[nt] = a; cm = fmaxf(cm, a);
      }
      cm = wmax16(cm);
      int rr = half*64 + 16*wv + 4*kq + r;
      float old = mxs2[rr];
      float nm = fmaxf(old, cm);
      float ss = 0.f;
      #pragma unroll
      for (int nt=0;nt<4;nt++) ss += __expf(av[nt] - nm);
      ss = wsum16(ss);
      if (l15 == 0){
        ses2[rr] = ses2[rr]*__expf(old - nm) + ss;
        mxs2[rr] = nm;
      }
    }
  }
  __syncthreads();
  if (tid < 64){
    float m0 = mxs2[tid], m1 = mxs2[64+tid];
    float nm = fmaxf(m0, m1);
    float se = ses2[tid]*__expf(m0-nm) + ses2[64+tid]*__expf(m1-nm);
    mxp[(size_t)ns*16384 + mt*64 + tid] = nm;
    sep[(size_t)ns*16384 + mt*64 + tid] = se;
  }
}

// pass2 with comb1 folded in: per-row running (mx, 1/se) computed from mxp/sep partials.
DEVI void pass2_body(int t256, int it, int jt, int b, const f16* tf, const f16* gdT,
                     const int* ys, const float* mxp, const float* sep, f16* scT,
                     f16* lA, f16* lB, int* jv, float* mxL, float* rseL){
  const int lane=t256&63, wv=t256>>6, l15=lane&15, kq=lane>>4;
  if (t256<64){
    jv[t256] = ys[b*512 + jt*64 + t256];
    int m = b*512 + it*64 + t256;
    float a0 = mxp[m], a1 = mxp[16384+m], a2 = mxp[2*16384+m], a3 = mxp[3*16384+m];
    float best = fmaxf(fmaxf(a0,a1), fmaxf(a2,a3));
    float sv = sep[m]*__expf(a0-best) + sep[16384+m]*__expf(a1-best)
             + sep[2*16384+m]*__expf(a2-best) + sep[3*16384+m]*__expf(a3-best);
    mxL[t256] = best; rseL[t256] = 1.f/sv;
  }
  const f16* A = tf + ((size_t)b*512 + it*64)*256;
  f32x4 acc[4]; ZERO4(acc);
  for (int k0=0;k0<256;k0+=32){
    __syncthreads();
    stage_tileh(t256, A + k0, 256, lA);
    { int row=t256>>2, qq=t256&3;
      *(f16x8*)(lB + row*LDT + qq*8) = *(const f16x8*)(gdT + (size_t)jv[row]*256 + k0 + qq*8); }
    __syncthreads();
    f16x8 af = frag_ld(lA + (16*wv+l15)*LDT + kq*8);
    #pragma unroll
    for (int nt=0;nt<4;nt++){
      f16x8 bf = frag_ld(lB + (16*nt+l15)*LDT + kq*8);
      acc[nt] = __builtin_amdgcn_mfma_f32_16x16x32_f16(af, bf, acc[nt], 0,0,0);
    }
  }
  float mxv[4], rsev[4];
  #pragma unroll
  for (int r=0;r<4;r++){
    int il = 16*wv + 4*kq + r;
    mxv[r] = mxL[il];
    rsev[r] = rseL[il];
  }
  #pragma unroll
  for (int nt=0;nt<4;nt++){
    int j_ = jt*64 + nt*16 + l15;
    #pragma unroll
    for (int r=0;r<4;r++){
      int i_ = it*64 + 16*wv + 4*kq + r;
      scT[((size_t)b*512 + j_)*512 + i_] = (f16)(__expf(acc[nt][r] - mxv[r]) * rsev[r]);
    }
  }
}

// k_final split 4-way over the i-range: is=blockIdx.x in [0,4), 2 ic-iters each
// (i0 = is*128 + ic*64). 1024 blocks -> ~3 blocks/CU (LDS-bound) instead of 2.
__global__ __launch_bounds__(256,2) void k_final(const f16* __restrict__ hdec, const f16* __restrict__ Th,
                                                 const f16* __restrict__ scT,
                                                 float* __restrict__ pmx, float* __restrict__ pden, float* __restrict__ pnum){
  __shared__ f16 lA[64*LDA];
  __shared__ f16 lB[64*LDT];
  __shared__ float mx_s[64], den_s[64], num_s[64];
  const int is = blockIdx.x, jt = blockIdx.y, b = blockIdx.z;
  const int tid = threadIdx.x, lane=tid&63, wv=tid>>6, l15=lane&15, kq=lane>>4;
  {
    const f16* A = hdec + ((size_t)b*512 + jt*64)*256;
    int row = tid>>2, qq = tid&3;
    #pragma unroll
    for (int c=0;c<8;c++)
      *(f16x8*)(lA + row*LDA + c*32 + qq*8) = *(const f16x8*)(A + (size_t)row*256 + c*32 + qq*8);
  }
  if (tid<64){ mx_s[tid]=-1e30f; den_s[tid]=0.f; num_s[tid]=0.f; }
  __syncthreads();
  for (int ic=0; ic<2; ic++){
    const int i0 = is*128 + ic*64;
    const f16* Bm = Th + ((size_t)b*512 + i0)*256;
    f32x4 acc[4]; ZERO4(acc);
    for (int k0=0;k0<256;k0+=32){
      __syncthreads();
      stage_tileh(tid, Bm + k0, 256, lB);
      __syncthreads();
      f16x8 af = frag_ld(lA + (16*wv+l15)*LDA + k0 + kq*8);
      #pragma unroll
      for (int nt=0;nt<4;nt++){
        f16x8 bf = frag_ld(lB + (16*nt+l15)*LDT + kq*8);
        acc[nt] = __builtin_amdgcn_mfma_f32_16x16x32_f16(af, bf, acc[nt], 0,0,0);
      }
    }
    #pragma unroll
    for (int r=0;r<4;r++){
      int jl = 16*wv + 4*kq + r;
      float av[4]; float cm=-1e30f;
      #pragma unroll
      for (int nt=0;nt<4;nt++){ av[nt]=acc[nt][r]; cm=fmaxf(cm,av[nt]); }
      cm = wmax16(cm);
      float old = mx_s[jl], nm = fmaxf(old, cm);
      float ds=0.f, nsum=0.f;
      const size_t srow = ((size_t)b*512 + jt*64 + jl)*512;
      #pragma unroll
      for (int nt=0;nt<4;nt++){
        float e = __expf(av[nt]-nm);
        float sc = (float)scT[srow + i0 + nt*16 + l15];
        ds += e; nsum += sc*e;
      }
      ds = wsum16(ds); nsum = wsum16(nsum);
      if (l15==0){
        float fac = __expf(old-nm);
        den_s[jl] = den_s[jl]*fac + ds;
        num_s[jl] = num_s[jl]*fac + nsum;
        mx_s[jl] = nm;
      }
    }
  }
  __syncthreads();
  if (tid<64){
    size_t idx = (((size_t)b*512) + jt*64 + tid)*4 + is;
    pmx[idx]=mx_s[tid]; pden[idx]=den_s[tid]; pnum[idx]=num_s[tid];
  }
}

__global__ void k_comb2(const float* __restrict__ pmx, const float* __restrict__ pden,
                        const float* __restrict__ pnum, float* __restrict__ out){
  const int b = blockIdx.x, j = threadIdx.x;    // 32 x 512
  size_t base = ((size_t)b*512 + j)*4;
  float m0=pmx[base], m1=pmx[base+1], m2=pmx[base+2], m3=pmx[base+3];
  float m = fmaxf(fmaxf(m0,m1), fmaxf(m2,m3));
  float e0=__expf(m0-m), e1=__expf(m1-m), e2=__expf(m2-m), e3=__expf(m3-m);
  float den = pden[base]*e0 + pden[base+1]*e1 + pden[base+2]*e2 + pden[base+3]*e3;
  float num = pnum[base]*e0 + pnum[base+1]*e1 + pnum[base+2]*e2 + pnum[base+3]*e3;
  float lp = __logf(num) - __logf(den);
  __shared__ float red[512];
  red[j] = lp;
  __syncthreads();
  for (int st=256; st>0; st>>=1){ if (j<st) red[j]+=red[j+st]; __syncthreads(); }
  if (j==0) atomicAdd(out, -red[0]);
}

// ---------------- LSTM v13: 2 seqs/block, 1 cell/thread (halved VALU phase) ----------------
// (verified R8: enc 389us, per-step ~1822cy = MFMA 1306 + VALU ~350 + exchange ~170)
DEVI void lstm_core(char* smem, const f16* U, const i32x4* Wq, const u32* ws,
                    u16* hout, float* hTcT, u16* hdec0, int nsteps, int mode, int bid)
{
  char* h8b = smem;                  // 2 buffers x 512 B
  const int tid = threadIdx.x;
  const int lane = tid & 63, w = tid >> 6;
  const int l15 = lane & 15, kq = lane >> 4;
  const int s = l15 & 1;             // sequence (2 per block)
  const int r = l15 >> 1;            // replica index -> owned tile 0..7
  const int u = w*32 + r*4 + kq;     // this thread's unit

  int dir = 0, b0;
  if (mode == 0){ dir = bid >> 4; b0 = (bid & 15)*2; }
  else b0 = bid*2;

  const float zscale = __uint_as_float(ws[0]) * (1.f/(127.f*127.f));

  i32x4 aw[32];
  #pragma unroll
  for (int f=0; f<32; f++) aw[f] = Wq[(size_t)(w*32 + f)*64 + lane];

  float c = 0.f;
  if (mode == 0){
    if (tid < 256) ((u32*)h8b)[tid] = 0u;   // 256 words = both 512B buffers
  } else {
    const float* hp = hTcT + (size_t)(b0+s)*512;
    float h0 = hp[u];
    c = hp[256 + u];
    h8b[((u>>4)*2 + s)*16 + (u&15)] = (char)(int)__builtin_rintf(h0*127.f);
  }

  // this thread's private U row base (unit-major cols: unit*4+gate)
  const f16* Urow = U + (size_t)(b0+s)*512*1024;
  f16x4 uv;
  {
    int tp0 = dir ? (nsteps-1) : 0;
    uv = *(const f16x4*)(Urow + (size_t)tp0*1024 + u*4);
  }
  __syncthreads();

  int cur = 0;
  #pragma unroll 1
  for (int t=0; t<nsteps; ++t){
    const int tpos = dir ? (nsteps-1-t) : t;
    int tn = dir ? (nsteps-2-t >= 0 ? nsteps-2-t : 0) : (t+1 < nsteps ? t+1 : nsteps-1);
    f16x4 pu = *(const f16x4*)(Urow + (size_t)tn*1024 + u*4);

    const char* hc = h8b + cur*512;
    i32x4 bf[4];
    #pragma unroll
    for (int kt=0; kt<4; kt++)
      bf[kt] = *(const i32x4*)(hc + ((kt*4 + kq)*2 + s)*16);

    i32x4 acc[8];
    #pragma unroll
    for (int t8=0; t8<8; t8++){
      i32x4 d = {0,0,0,0};
      #pragma unroll
      for (int kt=0; kt<4; kt++)
        d = __builtin_amdgcn_mfma_i32_16x16x64_i8(aw[t8*4+kt], bf[kt], d, 0,0,0);
      acc[t8] = d;
    }

    // pick tile r (7-select tree per element)
    i32x4 v;
    #pragma unroll
    for (int e=0; e<4; e++){
      int x01 = (r&1) ? acc[1][e] : acc[0][e];
      int x23 = (r&1) ? acc[3][e] : acc[2][e];
      int x45 = (r&1) ? acc[5][e] : acc[4][e];
      int x67 = (r&1) ? acc[7][e] : acc[6][e];
      int y0  = (r&2) ? x23 : x01;
      int y1  = (r&2) ? x67 : x45;
      v[e] = (r&4) ? y1 : y0;
    }

    float h_;
    {
      float z0 = fmaf((float)v[0], zscale, (float)uv[0]);
      float z1 = fmaf((float)v[1], zscale, (float)uv[1]);
      float z2 = fmaf((float)v[2], zscale, (float)uv[2]);
      float z3 = fmaf((float)v[3], zscale, (float)uv[3]);
      c  = sig_f(z1)*c + sig_f(z0)*tanh_f(z2);
      h_ = sig_f(z3)*tanh_f(c);
    }

    const int nxt = cur ^ 1;
    char* hn = h8b + nxt*512;
    hn[((u>>4)*2 + s)*16 + (u&15)] = (char)(int)__builtin_rintf(h_*127.f);

    f16 fh = (f16)h_;
    if (mode == 0){
      hout[(((size_t)(b0+s)*512 + tpos)*512) + dir*256 + u] = __builtin_bit_cast(u16, fh);
      if (!dir && t == nsteps-1){
        hdec0[(size_t)(b0+s)*512*256 + u] = __builtin_bit_cast(u16, fh);
        float* hp = hTcT + (size_t)(b0+s)*512;
        hp[u] = h_; hp[256+u] = c;
      }
    } else {
      hout[((size_t)(b0+s)*512 + (t+1))*256 + u] = __builtin_bit_cast(u16, fh);
    }

    // lgkm-only barrier: LDS h-exchange must be visible; global stores stay in flight.
    asm volatile("s_waitcnt lgkmcnt(0)" ::: "memory");
    __builtin_amdgcn_s_barrier();
    asm volatile("" ::: "memory");
    __builtin_amdgcn_sched_barrier(0);

    cur = nxt;
    uv = pu;
  }
}

// ---------------- mega dispatches: persistent-worker grids (proven R10 structure) ----------
__global__ __launch_bounds__(512,2) void k_mega_enc(
    const f16* __restrict__ Uenc, const i32x4* __restrict__ Wqe, const u32* __restrict__ wse,
    u16* __restrict__ henh, float* __restrict__ hTcT, u16* __restrict__ hdec0,
    const f16* __restrict__ tf, const f16* __restrict__ gdT,
    float* __restrict__ mxp, float* __restrict__ sep,
    const f16* __restrict__ yemb, const f16* __restrict__ Wihd,
    const float* __restrict__ db, f16* __restrict__ Udec)
{
  __shared__ __align__(16) char smem[45056];
  const int bid = blockIdx.x;
  const int tid = threadIdx.x;
  if (bid < 32){
    lstm_core(smem, Uenc, Wqe, wse, henh, hTcT, hdec0, 512, 0, bid);
    return;
  }
  if (bid >= 256 && bid < 288) return;   // keep LSTM CUs private
  const int w = (bid < 256) ? (bid - 32) : (bid - 64);   // 0..447
  for (int v = w; v < 3072; v += 448){
    __syncthreads();                      // smem reuse fence between jobs
    if (v < 1024){
      int mt = v >> 2;                    // 0..255
      int ns = v & 3;                     // 0..3
      pass1_body(tid, mt, ns, tf, gdT, mxp, sep,
                 (f16*)smem, (f16*)(smem + 33792), (float*)(smem + 44032), (float*)(smem + 44544));
    } else {
      int vb = v - 1024;                  // 0..2047
      int half = tid >> 8, t256 = tid & 255;
      int vbm = vb >> 4, ny = vb & 15;
      int m0 = (vbm*2 + half)*64;
      int n0 = ny*64;
      char* base = smem + half*10240;
      ku_body(t256, m0, n0, yemb, Wihd, db, Udec, (f16*)base, (f16*)(base + 5120));
    }
  }
}

__global__ __launch_bounds__(512,2) void k_mega_dec(
    const f16* __restrict__ Udec, const i32x4* __restrict__ Wqd, const u32* __restrict__ wsd,
    u16* __restrict__ hdec, float* __restrict__ hTcT,
    const f16* __restrict__ tf, const f16* __restrict__ gdT, const int* __restrict__ ys,
    const float* __restrict__ mxp, const float* __restrict__ sep, f16* __restrict__ scT,
    const f16* __restrict__ henh, const f16* __restrict__ Tf, f16* __restrict__ Th)
{
  __shared__ __align__(16) char smem[24576];
  const int bid = blockIdx.x;
  const int tid = threadIdx.x;
  if (bid < 16){
    lstm_core(smem, Udec, Wqd, wsd, hdec, hTcT, hdec, 511, 1, bid);
    return;
  }
  const int w = bid - 16;                // 0..495
  #pragma unroll 1
  for (int v = w; v < 1536; v += 496){
    __syncthreads();                      // smem reuse fence between jobs
    if (v < 1024){
      int half = tid >> 8, t256 = tid & 255;
      int b = v >> 5, rem = v & 31;
      int jt = rem >> 2, it = (rem & 3)*2 + half;
      char* base = smem + half*11008;
      pass2_body(t256, it, jt, b, tf, gdT, ys, mxp, sep, scT,
                 (f16*)base, (f16*)(base + 5120), (int*)(base + 10240),
                 (float*)(base + 10496), (float*)(base + 10752));
    } else {
      int vb = v - 1024;                  // 0..511
      int half = tid >> 8, t256 = tid & 255;
      int m0 = ((vb >> 2)*2 + half)*64;
      int n0 = (vb & 3)*64;
      char* base = smem + half*10240;
      th_body(t256, m0, n0, henh, Tf, Th, (f16*)base, (f16*)(base + 5120));
    }
  }
}

// ---------------- host ----------------
extern "C" void kernel_launch(void* const* d_in, const int* in_sizes, int n_in,
                              void* d_out, int out_size, void* d_ws, size_t ws_size,
                              hipStream_t stream)
{
  (void)in_sizes; (void)n_in; (void)out_size;
  const int*   xs    = (const int*)d_in[0];
  const int*   ys    = (const int*)d_in[1];
  const float* gemb  = (const float*)d_in[2];
  const float* gconv = (const float*)d_in[3];
  const float* gdec  = (const float*)d_in[4];
  const float* eemb  = (const float*)d_in[5];
  const float* demb  = (const float*)d_in[6];
  const float* eWih  = (const float*)d_in[7];
  const float* eWhh  = (const float*)d_in[8];
  const float* eb    = (const float*)d_in[9];
  const float* dWih  = (const float*)d_in[10];
  const float* dWhh  = (const float*)d_in[11];
  const float* db    = (const float*)d_in[12];
  const float* Tm    = (const float*)d_in[13];

  char* wsb = (char*)d_ws;
  size_t off = 0;
  auto take = [&](size_t bytes)->char*{ char* p = wsb + off; off += (bytes + 255) & ~(size_t)255; return p; };
  f16* epad  = (f16*)take((size_t)32*516*256*2);
  f16* tf    = (f16*)take((size_t)32*512*256*2);
  f16* xemb  = (f16*)take((size_t)32*512*128*2);
  f16* yemb  = (f16*)take((size_t)32*512*128*2);
  f16* Uenc  = (f16*)take((size_t)32*512*1024*2);
  f16* Udec  = (f16*)take((size_t)32*512*1024*2);
  f16* henh  = (f16*)take((size_t)32*512*512*2);
  f16* hdec  = (f16*)take((size_t)32*512*256*2);
  f16* Th    = (f16*)take((size_t)32*512*256*2);
  f16* scT   = (f16*)take((size_t)32*512*512*2);
  float* mxp = (float*)take((size_t)4*16384*4);
  float* sep = (float*)take((size_t)4*16384*4);
  float* pmx = (float*)take((size_t)32*512*4*4);
  float* pden= (float*)take((size_t)32*512*4*4);
  float* pnum= (float*)take((size_t)32*512*4*4);
  float* hTcT= (float*)take((size_t)32*512*4);
  f16* Wihe  = (f16*)take((size_t)1024*128*2);
  f16* Wihd  = (f16*)take((size_t)1024*128*2);
  f16* Tf    = (f16*)take((size_t)256*512*2);
  f16* gcT   = (f16*)take((size_t)256*1280*2);
  f16* gdT   = (f16*)take((size_t)2048*256*2);
  i32x4* Wq8e = (i32x4*)take((size_t)256*64*16);
  i32x4* Wq8d = (i32x4*)take((size_t)256*64*16);
  u32* wsc   = (u32*)take(16);
  if (off > ws_size) return;

  hipMemsetAsync(d_out, 0, sizeof(float), stream);
  hipMemsetAsync(wsc, 0, 16, stream);

  // fused prep 1: embx | cvt x3 | wmax x2 | epad | gconvT | gdecT
  k_prep1<<<dim3(38272), 256, 0, stream>>>(xs, ys, eemb, demb, xemb, yemb,
                                           eWih, Wihe, dWih, Wihd, Tm, Tf,
                                           eWhh, dWhh, wsc,
                                           gemb, epad, gconv, gcT, gdec, gdT);
  // fused prep 2: k_u enc | wq8 x2 | conv
  k_prep2<<<dim3(5632), 256, 0, stream>>>(xemb, Wihe, eb, Uenc, eWhh, dWhh, wsc,
                                          Wq8e, Wq8d, epad, gcT, tf);

  // mega-enc (persistent, 512 blocks): [0,32) lstm_enc | workers: 1024 pass1 + 2048 ku-dec
  k_mega_enc<<<dim3(512), 512, 0, stream>>>(Uenc, Wq8e, wsc + 0, (u16*)henh, hTcT, (u16*)hdec,
                                            tf, gdT, mxp, sep, yemb, Wihd, db, Udec);

  // mega-dec (persistent, 512 blocks): [0,16) lstm_dec | workers: 1024 pass2 (comb1 folded) + 512 th
  k_mega_dec<<<dim3(512), 512, 0, stream>>>(Udec, Wq8d, wsc + 1, (u16*)hdec, hTcT,
                                            tf, gdT, ys, mxp, sep, scT, henh, Tf, Th);

  k_final<<<dim3(4,8,32), 256, 0, stream>>>(hdec, Th, scT, pmx, pden, pnum);
  k_comb2<<<dim3(32), 512, 0, stream>>>(pmx, pden, pnum, (float*)d_out);
}